// Round 5
// baseline (28.338 us; speedup 1.0000x reference)
//
#include <hip/hip_runtime.h>
#include <math.h>

#define NVOX 16384
#define NRAYS 2048
#define STOPT 0.01f
#define FARP 100.0f

// ---------------- grid-culled path ----------------
#define NCELLS 512          // 8x8x8 over [-1,1]^3
#define CELLW 0.25f
#define PAD 0.051f          // max voxel half-size (0.05) + slack
#define CAPV 96             // per-cell capacity (mean 32, ~11 sigma)
#define MAXC 192            // per-ray hit-cell list capacity
#define CAPH 256            // per-ray hit list capacity

__global__ __launch_bounds__(512) void zero_kernel(int* __restrict__ cnt) {
    const int i = threadIdx.x;
    if (i < NCELLS) cnt[i] = 0;
}

__global__ __launch_bounds__(256) void bin_kernel(
    const float* __restrict__ pos, const float* __restrict__ siz,
    const float* __restrict__ den, int* __restrict__ cnt,
    float4* __restrict__ recs)
{
    const int v = blockIdx.x * 256 + threadIdx.x;
    if (v >= NVOX) return;
    const float px = pos[3*v], py = pos[3*v+1], pz = pos[3*v+2];
    const float h  = siz[v] * 0.5f;
    const int cx = min(7, max(0, (int)((px + 1.0f) * 4.0f)));
    const int cy = min(7, max(0, (int)((py + 1.0f) * 4.0f)));
    const int cz = min(7, max(0, (int)((pz + 1.0f) * 4.0f)));
    const int c  = cx + 8 * (cy + 8 * cz);
    const int slot = atomicAdd(&cnt[c], 1);
    if (slot < CAPV) {
        const int idx = (c * CAPV + slot) * 2;
        recs[idx]     = make_float4(px - h, py - h, pz - h, expf(den[v]));
        recs[idx + 1] = make_float4(px + h, py + h, pz + h, __int_as_float(v));
    }
}

__global__ __launch_bounds__(256) void raster_grid_kernel(
    const int* __restrict__ cnt, const float4* __restrict__ recs,
    const float* __restrict__ col,
    const float* __restrict__ rob, const float* __restrict__ rdb,
    float* __restrict__ out)
{
    __shared__ int   s_cells[MAXC];
    __shared__ float s_tn [CAPH];
    __shared__ float s_opv[CAPH];
    __shared__ int   s_cid[CAPH];
    __shared__ int   s_ncell, s_nhit;

    const int ray = blockIdx.x;
    const int tid = threadIdx.x;
    if (tid == 0) { s_ncell = 0; s_nhit = 0; }
    __syncthreads();

    const float ox = rob[ray*3], oy = rob[ray*3+1], oz = rob[ray*3+2];
    const float dx = rdb[ray*3], dy = rdb[ray*3+1], dz = rdb[ray*3+2];
    const float ivx = 1.0f/dx, ivy = 1.0f/dy, ivz = 1.0f/dz;
    const float ofx = -ox*ivx, ofy = -oy*ivy, ofz = -oz*ivz;

    // Phase A: slab-test all 512 padded cell AABBs (conservative cull)
    for (int c = tid; c < NCELLS; c += 256) {
        const int cx = c & 7, cy = (c >> 3) & 7, cz = c >> 6;
        const float mnx = -1.0f + CELLW*cx - PAD, mxx = mnx + CELLW + 2.0f*PAD;
        const float mny = -1.0f + CELLW*cy - PAD, mxy = mny + CELLW + 2.0f*PAD;
        const float mnz = -1.0f + CELLW*cz - PAD, mxz = mnz + CELLW + 2.0f*PAD;
        const float t0x = fmaf(mnx, ivx, ofx), t1x = fmaf(mxx, ivx, ofx);
        const float t0y = fmaf(mny, ivy, ofy), t1y = fmaf(mxy, ivy, ofy);
        const float t0z = fmaf(mnz, ivz, ofz), t1z = fmaf(mxz, ivz, ofz);
        const float tn = fmaxf(fmaxf(fminf(t0x,t1x), fminf(t0y,t1y)), fminf(t0z,t1z));
        const float tf = fminf(fminf(fmaxf(t0x,t1x), fmaxf(t0y,t1y)), fmaxf(t0z,t1z));
        if (tf >= tn && tf > 0.0f) {
            const int k = atomicAdd(&s_ncell, 1);
            if (k < MAXC) s_cells[k] = c;
        }
    }
    __syncthreads();

    // Phase B: waves round-robin hit cells; lanes test member voxels
    const int wv = tid >> 6, lane = tid & 63;
    const int nc = min(s_ncell, MAXC);
    for (int ci = wv; ci < nc; ci += 4) {
        const int c = s_cells[ci];
        const int m = min(cnt[c], CAPV);
        for (int j = lane; j < m; j += 64) {
            const float4 A = recs[(c*CAPV + j)*2];
            const float4 B = recs[(c*CAPV + j)*2 + 1];
            const float t0x = fmaf(A.x, ivx, ofx), t1x = fmaf(B.x, ivx, ofx);
            const float t0y = fmaf(A.y, ivy, ofy), t1y = fmaf(B.y, ivy, ofy);
            const float t0z = fmaf(A.z, ivz, ofz), t1z = fmaf(B.z, ivz, ofz);
            const float tn = fmaxf(fmaxf(fminf(t0x,t1x), fminf(t0y,t1y)), fminf(t0z,t1z));
            const float tf = fminf(fminf(fmaxf(t0x,t1x), fmaxf(t0y,t1y)), fmaxf(t0z,t1z));
            if (tf > tn && tf > 0.0f) {
                const float op = 1.0f - expf(-A.w * (tf - tn) * (1.0f/7.0f));
                const int k = atomicAdd(&s_nhit, 1);
                if (k < CAPH) {
                    s_tn[k]  = tn;
                    s_opv[k] = op;
                    s_cid[k] = __float_as_int(B.w);
                }
            }
        }
    }
    __syncthreads();

    // Phase C: wave 0 composites via O(n^2) exclusive product
    // (reference semantics: w_i = T_excl_i*op_i if T_excl_i >= STOP_T)
    if (wv == 0) {
        const int n = min(s_nhit, CAPH);
        float ar = 0.f, ag = 0.f, ab = 0.f, ad = 0.f, aw = 0.f;
        for (int i = lane; i < n; i += 64) {
            const float ti = s_tn[i], oi = s_opv[i];
            float T = 1.0f;
            for (int j = 0; j < n; ++j)
                T *= (s_tn[j] < ti) ? (1.0f - s_opv[j]) : 1.0f;
            const float w = (T >= STOPT) ? T * oi : 0.0f;
            const int c = s_cid[i];
            ar += w * col[c*3+0];
            ag += w * col[c*3+1];
            ab += w * col[c*3+2];
            ad += w * ti;
            aw += w;
        }
#pragma unroll
        for (int off = 32; off > 0; off >>= 1) {
            ar += __shfl_down(ar, off);
            ag += __shfl_down(ag, off);
            ab += __shfl_down(ab, off);
            ad += __shfl_down(ad, off);
            aw += __shfl_down(aw, off);
        }
        if (lane == 0) {
            out[ray*3+0] = ar;
            out[ray*3+1] = ag;
            out[ray*3+2] = ab;
            out[NRAYS*3 + ray] = (n > 0) ? ad : FARP;
            out[NRAYS*4 + ray] = aw;
        }
    }
}

// ---------------- flat fallback (round-4 kernel) ----------------
#define FB_CAP 256
#define FB_BLK 1024
#define FB_RPB 4

__global__ __launch_bounds__(FB_BLK) void raster_flat_kernel(
    const float* __restrict__ pos, const float* __restrict__ siz,
    const float* __restrict__ den, const float* __restrict__ col,
    const float* __restrict__ rob, const float* __restrict__ rdb,
    float* __restrict__ out)
{
    __shared__ float s_key[FB_RPB][FB_CAP];
    __shared__ float s_op [FB_RPB][FB_CAP];
    __shared__ int   s_cid[FB_RPB][FB_CAP];
    __shared__ int   s_cnt[FB_RPB];

    const int tid  = threadIdx.x;
    const int ray0 = blockIdx.x * FB_RPB;
    if (tid < FB_RPB) s_cnt[tid] = 0;
    __syncthreads();

    float ivx[FB_RPB], ivy[FB_RPB], ivz[FB_RPB], ofx[FB_RPB], ofy[FB_RPB], ofz[FB_RPB];
#pragma unroll
    for (int r = 0; r < FB_RPB; ++r) {
        const int ray = ray0 + r;
        const float ox = rob[ray*3], oy = rob[ray*3+1], oz = rob[ray*3+2];
        const float dx = rdb[ray*3], dy = rdb[ray*3+1], dz = rdb[ray*3+2];
        ivx[r] = 1.0f/dx; ivy[r] = 1.0f/dy; ivz[r] = 1.0f/dz;
        ofx[r] = -ox*ivx[r]; ofy[r] = -oy*ivy[r]; ofz[r] = -oz*ivz[r];
    }
#pragma unroll 4
    for (int v = tid; v < NVOX; v += FB_BLK) {
        const float px = pos[3*v], py = pos[3*v+1], pz = pos[3*v+2];
        const float h = siz[v]*0.5f;
        const float bnx = px-h, bxx = px+h, bny = py-h, bxy = py+h, bnz = pz-h, bxz = pz+h;
#pragma unroll
        for (int r = 0; r < FB_RPB; ++r) {
            const float t0x = fmaf(bnx, ivx[r], ofx[r]), t1x = fmaf(bxx, ivx[r], ofx[r]);
            const float t0y = fmaf(bny, ivy[r], ofy[r]), t1y = fmaf(bxy, ivy[r], ofy[r]);
            const float t0z = fmaf(bnz, ivz[r], ofz[r]), t1z = fmaf(bxz, ivz[r], ofz[r]);
            const float tn = fmaxf(fmaxf(fminf(t0x,t1x), fminf(t0y,t1y)), fminf(t0z,t1z));
            const float tf = fminf(fminf(fmaxf(t0x,t1x), fmaxf(t0y,t1y)), fmaxf(t0z,t1z));
            if (tf > tn && tf > 0.0f) {
                const float op = 1.0f - expf(-expf(den[v]) * (tf - tn) * (1.0f/7.0f));
                const int k = atomicAdd(&s_cnt[r], 1);
                if (k < FB_CAP) { s_key[r][k] = tn; s_op[r][k] = op; s_cid[r][k] = v; }
            }
        }
    }
    __syncthreads();

    const int wv = tid >> 6, lane = tid & 63;
    if (wv < FB_RPB) {
        const int n = min(s_cnt[wv], FB_CAP);
        float ar = 0.f, ag = 0.f, ab = 0.f, ad = 0.f, aw = 0.f;
        for (int i = lane; i < n; i += 64) {
            const float ti = s_key[wv][i], oi = s_op[wv][i];
            float T = 1.0f;
            for (int j = 0; j < n; ++j)
                T *= (s_key[wv][j] < ti) ? (1.0f - s_op[wv][j]) : 1.0f;
            const float w = (T >= STOPT) ? T * oi : 0.0f;
            const int c = s_cid[wv][i];
            ar += w*col[c*3+0]; ag += w*col[c*3+1]; ab += w*col[c*3+2];
            ad += w*ti; aw += w;
        }
#pragma unroll
        for (int off = 32; off > 0; off >>= 1) {
            ar += __shfl_down(ar, off); ag += __shfl_down(ag, off);
            ab += __shfl_down(ab, off); ad += __shfl_down(ad, off);
            aw += __shfl_down(aw, off);
        }
        if (lane == 0) {
            const int ray = ray0 + wv;
            out[ray*3+0] = ar; out[ray*3+1] = ag; out[ray*3+2] = ab;
            out[NRAYS*3 + ray] = (n > 0) ? ad : FARP;
            out[NRAYS*4 + ray] = aw;
        }
    }
}

extern "C" void kernel_launch(void* const* d_in, const int* in_sizes, int n_in,
                              void* d_out, int out_size, void* d_ws, size_t ws_size,
                              hipStream_t stream) {
    const float* pos = (const float*)d_in[0];
    const float* siz = (const float*)d_in[1];
    const float* den = (const float*)d_in[2];
    const float* col = (const float*)d_in[3];
    const float* rob = (const float*)d_in[4];
    const float* rdb = (const float*)d_in[5];
    float* out = (float*)d_out;

    const size_t need = 4096 + (size_t)NCELLS * CAPV * 2 * sizeof(float4);
    if (ws_size >= need) {
        int*    cnt  = (int*)d_ws;
        float4* recs = (float4*)((char*)d_ws + 4096);
        zero_kernel<<<1, 512, 0, stream>>>(cnt);
        bin_kernel<<<NVOX/256, 256, 0, stream>>>(pos, siz, den, cnt, recs);
        raster_grid_kernel<<<NRAYS, 256, 0, stream>>>(cnt, recs, col, rob, rdb, out);
    } else {
        raster_flat_kernel<<<NRAYS/FB_RPB, FB_BLK, 0, stream>>>(pos, siz, den, col, rob, rdb, out);
    }
}